// Round 10
// baseline (77.001 us; speedup 1.0000x reference)
//
#include <hip/hip_runtime.h>

#define N2    8192
#define NTILE 2080   // 64*65/2 upper-triangle 128x128 blocks
#define NPB   256    // persistent blocks (1/CU; capacity 2/CU guaranteed)

static constexpr float INV_T = 1.0f / 0.07f;

using f32x4 = __attribute__((ext_vector_type(4))) float;
using i32x4 = __attribute__((ext_vector_type(4))) int;
using i32x8 = __attribute__((ext_vector_type(8))) int;
typedef unsigned int u32;

#define GL2LDS(gp, lp) __builtin_amdgcn_global_load_lds( \
    (const __attribute__((address_space(1))) void*)(gp), \
    (__attribute__((address_space(3))) void*)(lp), 16, 0, 0)
#define SCALE1 0x7F7F7F7F   // E8M0 127 = 2^0 per byte -> scale 1.0

__device__ __forceinline__ void decode_tri(int t, int& br, int& bc) {
    int b = (int)((129.0f - sqrtf(16641.0f - 8.0f * (float)t)) * 0.5f);
    while ((b + 1) * (129 - (b + 1)) / 2 <= t) ++b;
    while (b * (129 - b) / 2 > t) --b;
    br = b; bc = b + (t - b * (129 - b) / 2);
}

// ---------- kernel 1: normalize rows f32 -> fp8 e4m3; zero grid-barrier state ----------
__global__ void ntx_norm(const float* __restrict__ z1, const float* __restrict__ z2,
                         unsigned char* __restrict__ zn, u32* __restrict__ bar)
{
    if (blockIdx.x == 0 && threadIdx.x < 4) bar[threadIdx.x] = 0;

    const int w = threadIdx.x >> 6, lane = threadIdx.x & 63;
    const int row = blockIdx.x * 4 + w;
    const float* src = (row < 4096) ? z1 + (size_t)row * 256 : z2 + (size_t)(row - 4096) * 256;
    float4 v = *(const float4*)(src + lane * 4);
    float ss = v.x*v.x + v.y*v.y + v.z*v.z + v.w*v.w;
    #pragma unroll
    for (int m = 1; m < 64; m <<= 1) ss += __shfl_xor(ss, m, 64);
    float inv = 1.0f / fmaxf(sqrtf(ss), 1e-8f);
    u32 p = __builtin_amdgcn_cvt_pk_fp8_f32(v.x*inv, v.y*inv, 0u, false);
    p     = __builtin_amdgcn_cvt_pk_fp8_f32(v.z*inv, v.w*inv, p, true);
    ((u32*)zn)[(size_t)row * 64 + lane] = p;
}

// ---------- kernel 2: persistent — gemm tile loop + grid barrier + loss + mean ----------
// Per tile: full-K LDS (A,B = 128 rows x 256 B fp8, 64 KB), GL2LDS staging with
// rule-21 swizzle pair; next tile staged UNDER current epilogue (LDS dead after MFMA).
// MX-scaled fp8 MFMA K=128 (R8-proven). Grid barriers: device-scope atomics,
// state zeroed by ntx_norm each launch (R7/R8 fence pattern, validated).
__global__ __launch_bounds__(256, 2)
void ntx_main(const unsigned char* __restrict__ zn, float* __restrict__ partials,
              float* __restrict__ pos, float* __restrict__ bsums,
              u32* __restrict__ bar, float* __restrict__ out)
{
    __shared__ __align__(16) unsigned char lsA[32768];
    __shared__ __align__(16) unsigned char lsB[32768];
    __shared__ float smf[4];

    const int tid = threadIdx.x, lane = tid & 63, w = tid >> 6;
    const int wr = w >> 1, wc = w & 1;
    const int fr = lane & 15, kl = lane >> 4;
    const int swz = (fr & 7) << 4;
    const int bid = (int)blockIdx.x;

    // staging: per issue, 256 threads cover 16 rows x 16 granules of 16 B.
    // LDS linear dest; global source col = c ^ ((row&7)<<4)  (involution with read swz)
    const int sr   = tid >> 4;                       // row-within-16 (0..15)
    const int scsw = ((tid & 15) * 16) ^ ((sr & 7) << 4);

    auto stage = [&](int br_, int bc_) {
        const char* gA = (const char*)zn + (size_t)(br_ * 128 + sr) * 256 + scsw;
        const char* gB = (const char*)zn + (size_t)(bc_ * 128 + sr) * 256 + scsw;
        #pragma unroll
        for (int i = 0; i < 8; ++i) {                // +16 rows = 4096 B per issue
            GL2LDS(gA + (size_t)i * 4096, lsA + i * 4096 + w * 1024);
            GL2LDS(gB + (size_t)i * 4096, lsB + i * 4096 + w * 1024);
        }
    };

    { int br0, bc0; decode_tri(bid, br0, bc0); stage(br0, bc0); }

    for (int t = bid; t < NTILE; t += NPB) {
        int br, bc; decode_tri(t, br, bc);

        f32x4 acc[4][4] = {};

        __syncthreads();               // drains vmcnt: staged tile visible

        #pragma unroll
        for (int kt = 0; kt < 2; ++kt) {
            const int kb = kt * 128 + kl * 32;
            i32x8 af[4], bv[4];
            #pragma unroll
            for (int mf = 0; mf < 4; ++mf) {
                const char* base = (const char*)lsA + (wr*64 + mf*16 + fr) * 256;
                i32x4 lo = *(const i32x4*)(base + ((kb)      ^ swz));
                i32x4 hi = *(const i32x4*)(base + ((kb + 16) ^ swz));
                af[mf] = (i32x8){lo[0],lo[1],lo[2],lo[3],hi[0],hi[1],hi[2],hi[3]};
            }
            #pragma unroll
            for (int nf = 0; nf < 4; ++nf) {
                const char* base = (const char*)lsB + (wc*64 + nf*16 + fr) * 256;
                i32x4 lo = *(const i32x4*)(base + ((kb)      ^ swz));
                i32x4 hi = *(const i32x4*)(base + ((kb + 16) ^ swz));
                bv[nf] = (i32x8){lo[0],lo[1],lo[2],lo[3],hi[0],hi[1],hi[2],hi[3]};
            }
            __builtin_amdgcn_s_setprio(1);
            #pragma unroll
            for (int mf = 0; mf < 4; ++mf)
                #pragma unroll
                for (int nf = 0; nf < 4; ++nf)
                    acc[mf][nf] = __builtin_amdgcn_mfma_scale_f32_16x16x128_f8f6f4(
                        af[mf], bv[nf], acc[mf][nf], 0, 0, 0, SCALE1, 0, SCALE1);
            __builtin_amdgcn_s_setprio(0);
        }

        __syncthreads();               // all waves done reading LDS

        const int tn = t + NPB;        // prefetch next tile under the epilogue
        if (tn < NTILE) { int brn, bcn; decode_tri(tn, brn, bcn); stage(brn, bcn); }

        // ---- epilogue (R8-proven): e = exp((dot-1)/T), diag masked ----
        const bool offdiag = (br != bc);
        const bool posblk  = (bc == br + 32);
        float colsum[4] = {0.f, 0.f, 0.f, 0.f};

        #pragma unroll
        for (int mf = 0; mf < 4; ++mf) {
            float rs[4] = {0.f, 0.f, 0.f, 0.f};
            const int rowq = br*128 + wr*64 + mf*16 + kl*4;
            #pragma unroll
            for (int nf = 0; nf < 4; ++nf) {
                const int col = bc*128 + wc*64 + nf*16 + fr;
                f32x4 a = acc[mf][nf];
                #pragma unroll
                for (int j = 0; j < 4; ++j) {
                    float e = (rowq + j == col) ? 0.f : __expf((a[j] - 1.0f) * INV_T);
                    rs[j]      += e;
                    colsum[nf] += e;
                    if (posblk && (rowq + j + 4096 == col)) {
                        pos[rowq + j] = a[j];
                        pos[col]      = a[j];
                    }
                }
            }
            #pragma unroll
            for (int m = 1; m < 16; m <<= 1) {
                #pragma unroll
                for (int j = 0; j < 4; ++j) rs[j] += __shfl_xor(rs[j], m, 64);
            }
            if (fr == 0) {
                float* p = partials + (size_t)rowq*128 + bc*2 + wc;
                p[0]=rs[0]; p[128]=rs[1]; p[256]=rs[2]; p[384]=rs[3];
            }
        }
        if (offdiag) {
            #pragma unroll
            for (int m = 16; m < 64; m <<= 1) {
                #pragma unroll
                for (int nf = 0; nf < 4; ++nf) colsum[nf] += __shfl_xor(colsum[nf], m, 64);
            }
            if (kl == 0) {
                #pragma unroll
                for (int nf = 0; nf < 4; ++nf) {
                    const int col = bc*128 + wc*64 + nf*16 + fr;
                    partials[(size_t)col*128 + br*2 + wr] = colsum[nf];
                }
            }
        }
    }

    // ---- grid barrier 0: all partials/pos written ----
    __syncthreads();
    if (tid == 0) {
        __threadfence();                             // release this block's writes
        u32 old = atomicAdd(&bar[0], 1u);
        if (old == NPB - 1u) { __threadfence(); atomicExch(&bar[1], 1u); }
        else while (atomicAdd(&bar[1], 0u) == 0u) __builtin_amdgcn_s_sleep(8);
        __threadfence();                             // acquire
    }
    __syncthreads();

    // ---- loss phase: 32 rows per block ----
    float a = 0.f;
    #pragma unroll
    for (int i = 0; i < 8; ++i) {
        const int row = bid * 32 + w * 8 + i;
        float S = partials[(size_t)row*128 + lane] + partials[(size_t)row*128 + 64 + lane];
        #pragma unroll
        for (int m = 1; m < 64; m <<= 1) S += __shfl_xor(S, m, 64);
        if (lane == 0) a += __logf(S) + INV_T - pos[row] * INV_T;
    }
    if (lane == 0) smf[w] = a;
    __syncthreads();
    if (tid == 0) {
        bsums[bid] = smf[0] + smf[1] + smf[2] + smf[3];
        __threadfence();                             // release block sum
        atomicAdd(&bar[2], 1u);                      // arrive (no wait needed except block 0)
    }

    // ---- block 0 waits for all block sums, then fixed-order mean ----
    if (bid == 0) {
        if (tid == 0) {
            while (atomicAdd(&bar[2], 0u) < (u32)NPB) __builtin_amdgcn_s_sleep(8);
            __threadfence();                         // acquire
        }
        __syncthreads();
        float v = bsums[tid];
        #pragma unroll
        for (int m = 1; m < 64; m <<= 1) v += __shfl_xor(v, m, 64);
        if (lane == 0) smf[w] = v;
        __syncthreads();
        if (tid == 0) out[0] = (smf[0] + smf[1] + smf[2] + smf[3]) * (1.0f / (float)N2);
    }
}

extern "C" void kernel_launch(void* const* d_in, const int* in_sizes, int n_in,
                              void* d_out, int out_size, void* d_ws, size_t ws_size,
                              hipStream_t stream)
{
    const float* z1 = (const float*)d_in[0];
    const float* z2 = (const float*)d_in[1];
    float* out = (float*)d_out;

    // workspace layout
    unsigned char* zn       = (unsigned char*)d_ws;                    // 2 MB
    float*         partials = (float*)((char*)d_ws + (2u << 20));      // 4 MB
    float*         pos      = (float*)((char*)d_ws + (6u << 20));      // 32 KB
    float*         bsums    = pos + N2;                                // 1 KB
    u32*           bar      = (u32*)(bsums + NPB);                     // 16 B

    ntx_norm<<<N2 / 4, 256, 0, stream>>>(z1, z2, zn, bar);
    ntx_main<<<NPB, 256, 0, stream>>>(zn, partials, pos, bsums, bar, out);
}